// Round 1
// baseline (1004.137 us; speedup 1.0000x reference)
//
#include <hip/hip_runtime.h>

// SESConv: out[b,o,g,h,w] = sum_{i,j,ic,x,y} X[b,ic,srcslice,h+x-2,w+y-2] * Kc[g,o,ic,2i+j,x,y]
// Kc[g,o,ic,r,x,y] = sum_f weight[o,ic,r,f]*basis[f,g,x,y]
// x: (8,16,12,128,128) f32; weight: (16,16,4,9); basis: (9,12,5,5); out: (8,16,12,128,128)

#define NRS 12
#define CIN 16
#define COUT 16
#define HW 128
#define IMG (HW*HW)

// Kc layout in workspace: [g(12)][r(4)][ic(16)][xy(25)][o(16)]  (o contiguous for float4)
__global__ void build_kc(const float* __restrict__ wgt, const float* __restrict__ basis,
                         float* __restrict__ kc) {
    int idx = blockIdx.x * 256 + threadIdx.x;
    const int total = NRS * 4 * CIN * 25 * COUT;   // 307200
    if (idx >= total) return;
    int o  = idx & 15;
    int t  = idx >> 4;
    int xy = t % 25; t /= 25;
    int ic = t & 15; t >>= 4;
    int r  = t & 3;
    int g  = t >> 2;
    int xk = xy / 5, yk = xy - 5 * xk;
    float s = 0.f;
    #pragma unroll
    for (int f = 0; f < 9; ++f)
        s = fmaf(wgt[((o * CIN + ic) * 4 + r) * 9 + f],
                 basis[((f * NRS + g) * 5 + xk) * 5 + yk], s);
    kc[idx] = s;
}

__global__ __launch_bounds__(256, 2)
void conv_main(const float* __restrict__ x, const float* __restrict__ kc,
               float* __restrict__ out) {
    const int b   = blockIdx.z;
    const int g   = blockIdx.y;
    const int th0 = (blockIdx.x >> 2) * 32;   // tile origin h
    const int tw0 = (blockIdx.x & 3) * 32;    // tile origin w
    const int r0 = g / 3, s0 = g - 3 * r0;

    const int t   = threadIdx.x;
    const int row = t >> 3;            // 0..31
    const int wq  = (t & 7) << 2;      // 0,4,...,28 (4 consecutive w per thread)

    // stride 37 breaks the 8-way bank conflict of stride 36/40 down to free 2-way
    __shared__ float xs[8][36][37];    // 42624 B -> 3 blocks/CU by LDS

    float acc[16][4];
    #pragma unroll
    for (int o = 0; o < 16; ++o)
        #pragma unroll
        for (int p = 0; p < 4; ++p) acc[o][p] = 0.f;

    for (int i = 0; i < 2; ++i) {
        int rr = r0 + i; if (rr >= 4) rr -= 4;          // circular in r
        for (int j = 0; j < 2; ++j) {
            int ss = s0 + j;
            if (ss >= 3) continue;                       // zero-pad slice in s
            const int sin_ = rr * 3 + ss;
            const float* xb = x + ((size_t)(b * CIN) * NRS + sin_) * IMG;
            const int rbase = 2 * i + j;
            for (int ich = 0; ich < 16; ich += 8) {
                __syncthreads();
                // stage 8 input channels, 36x36 halo tile (zero-fill outside image)
                for (int l = t; l < 8 * 36 * 36; l += 256) {
                    int ic  = l / (36 * 36);
                    int rem = l - ic * (36 * 36);
                    int rl  = rem / 36;
                    int cl  = rem - rl * 36;
                    int hh = th0 + rl - 2;
                    int ww = tw0 + cl - 2;
                    float v = 0.f;
                    if ((unsigned)hh < 128u && (unsigned)ww < 128u)
                        v = xb[(size_t)(ich + ic) * (NRS * IMG) + hh * HW + ww];
                    xs[ic][rl][cl] = v;
                }
                __syncthreads();
                const float* kcb = kc + (((size_t)g * 4 + rbase) * CIN + ich) * (25 * 16);
                for (int ic = 0; ic < 8; ++ic) {
                    for (int xk = 0; xk < 5; ++xk) {
                        float xw[8];
                        #pragma unroll
                        for (int q = 0; q < 8; ++q) xw[q] = xs[ic][row + xk][wq + q];
                        const float4* kc4 =
                            (const float4*)(kcb + (ic * 25 + xk * 5) * 16);
                        #pragma unroll
                        for (int yk = 0; yk < 5; ++yk) {
                            #pragma unroll
                            for (int oq = 0; oq < 4; ++oq) {
                                float4 kv = kc4[yk * 4 + oq];
                                #pragma unroll
                                for (int p = 0; p < 4; ++p) {
                                    acc[oq*4+0][p] = fmaf(xw[yk+p], kv.x, acc[oq*4+0][p]);
                                    acc[oq*4+1][p] = fmaf(xw[yk+p], kv.y, acc[oq*4+1][p]);
                                    acc[oq*4+2][p] = fmaf(xw[yk+p], kv.z, acc[oq*4+2][p]);
                                    acc[oq*4+3][p] = fmaf(xw[yk+p], kv.w, acc[oq*4+3][p]);
                                }
                            }
                        }
                    }
                }
            }
        }
    }

    float* ob = out + (((size_t)(b * COUT)) * NRS + g) * IMG + (th0 + row) * HW + tw0 + wq;
    #pragma unroll
    for (int o = 0; o < 16; ++o) {
        float4 v = make_float4(acc[o][0], acc[o][1], acc[o][2], acc[o][3]);
        *reinterpret_cast<float4*>(ob + (size_t)o * (NRS * IMG)) = v;
    }
}

extern "C" void kernel_launch(void* const* d_in, const int* in_sizes, int n_in,
                              void* d_out, int out_size, void* d_ws, size_t ws_size,
                              hipStream_t stream) {
    const float* x      = (const float*)d_in[0];
    const float* weight = (const float*)d_in[1];
    const float* basis  = (const float*)d_in[2];
    float* out = (float*)d_out;
    float* kc  = (float*)d_ws;   // needs 307200*4 = 1.23 MB

    build_kc<<<dim3((NRS*4*CIN*25*COUT + 255) / 256), dim3(256), 0, stream>>>(weight, basis, kc);
    conv_main<<<dim3(16, NRS, 8), dim3(256), 0, stream>>>(x, kc, out);
}

// Round 2
// 284.100 us; speedup vs baseline: 3.5344x; 3.5344x over previous
//
#include <hip/hip_runtime.h>

// SESConv via implicit GEMM on bf16 MFMA (gfx950).
// out[b,o,g,h,w] = sum_{rbase valid, ic, xk, yk} Kc[g,rbase,pos,ic,o] * X[b,ic,src(g,rbase), h+xk-2, w+yk-2]
// Kc[...] = sum_f weight[o,ic,rbase,f] * basis[f,g,xk,yk]
// x: (8,16,12,128,128) f32; weight: (16,16,4,9) f32; basis: (9,12,5,5) f32; out: (8,16,12,128,128) f32

#define NRS 12
#define CIN 16
#define COUT 16
#define HW 128
#define IMG (HW*HW)
#define ICSTRIDE (NRS*IMG)        // x stride between input channels (floats)
#define HALO 36
#define NPIX (HALO*HALO)          // 1296 halo pixels per slice tile
#define HALFBYTES (NPIX*8*2)      // 20736 B per ic-half in LDS
#define ROWB (HALO*16)            // 576 B per halo row (16 B per pixel)

typedef __bf16 bf16x8 __attribute__((ext_vector_type(8)));
typedef float  f32x4  __attribute__((ext_vector_type(4)));

__device__ __forceinline__ unsigned short f2bf(float f) {
    unsigned u = __builtin_bit_cast(unsigned, f);
    u += 0x7fffu + ((u >> 16) & 1u);          // round-nearest-even
    return (unsigned short)(u >> 16);
}

// A-panel: [g(12)][rbase(4)][pp(13)][o(16)][k(32)] bf16, k = possel*16 + ic, pos = 2*pp+possel
// pos==25 -> 0 (pad). 319488 elems = 639 KB.
__global__ void build_kc(const float* __restrict__ wgt, const float* __restrict__ basis,
                         unsigned short* __restrict__ kc) {
    int idx = blockIdx.x * 256 + threadIdx.x;
    const int total = 12 * 4 * 13 * 16 * 32;   // 319488
    if (idx >= total) return;
    int k  = idx & 31;
    int possel = k >> 4, ic = k & 15;
    int o  = (idx >> 5) & 15;
    int t2 = idx >> 9;
    int pp = t2 % 13;
    int gr = t2 / 13;
    int rbase = gr & 3, g = gr >> 2;
    int pos = 2 * pp + possel;
    float s = 0.f;
    if (pos < 25) {
        int xk = pos / 5, yk = pos - 5 * xk;
        #pragma unroll
        for (int f = 0; f < 9; ++f)
            s = fmaf(wgt[((o * CIN + ic) * 4 + rbase) * 9 + f],
                     basis[((f * NRS + g) * 5 + xk) * 5 + yk], s);
    }
    kc[idx] = f2bf(s);
}

__global__ __launch_bounds__(256, 2)
void conv_mfma(const float* __restrict__ x, const unsigned short* __restrict__ kc,
               float* __restrict__ out) {
    const int b   = blockIdx.z;
    const int g   = blockIdx.y;
    const int th0 = (blockIdx.x >> 2) * 32;
    const int tw0 = (blockIdx.x & 3) * 32;
    const int r0 = g / 3, s0 = g - 3 * r0;

    const int t    = threadIdx.x;
    const int lane = t & 63;
    const int wave = t >> 6;
    const int n    = lane & 15;        // MFMA N index (pixel within group)
    const int q    = lane >> 4;        // quad: possel = q>>1, ic-half = q&1
    const int possel = q >> 1;
    const int half_  = q & 1;

    __shared__ uint4 xs4[(2 * HALFBYTES) / 16];   // 41472 B
    char* xsc = (char*)xs4;

    // per-lane B-fragment byte offsets per K-step (tap pair), fixed for whole kernel
    int boff[13];
    #pragma unroll
    for (int pp = 0; pp < 13; ++pp) {
        int pos = 2 * pp + possel; if (pos > 24) pos = 24;   // pad tap reads tap 24; A=0 there
        int dx = pos / 5, dy = pos - 5 * dx;
        boff[pp] = half_ * HALFBYTES + dx * ROWB + (n + dy) * 16;
    }
    const int aoff = (lane & 15) * 32 + (lane >> 4) * 8;     // A-frag: o*32 + q*8 (ushort elems)

    f32x4 acc[16];
    #pragma unroll
    for (int pg = 0; pg < 16; ++pg) acc[pg] = (f32x4){0.f, 0.f, 0.f, 0.f};

    for (int i = 0; i < 2; ++i) {
        int rr = r0 + i; if (rr >= 4) rr -= 4;
        for (int j = 0; j < 2; ++j) {
            int ss = s0 + j;
            if (ss >= 3) continue;                 // zero-pad slice in s
            const int sin_  = rr * 3 + ss;
            const int rbase = 2 * i + j;
            const float* xb = x + ((size_t)b * CIN * NRS + sin_) * IMG;

            __syncthreads();                       // protect xs from previous slice's readers
            // ---- stage 36x36 halo, 16 ic, fp32->bf16, layout [half][pix][icq] ----
            for (int p = t; p < NPIX; p += 256) {
                int rl = p / HALO, cl = p - rl * HALO;
                int hh = th0 + rl - 2, ww = tw0 + cl - 2;
                bool ok = ((unsigned)hh < 128u) && ((unsigned)ww < 128u);
                const float* px = xb + hh * HW + ww;
                unsigned short v[16];
                #pragma unroll
                for (int ic = 0; ic < 16; ++ic) {
                    float f = 0.f;
                    if (ok) f = px[(size_t)ic * ICSTRIDE];
                    v[ic] = f2bf(f);
                }
                uint4 lo, hi;
                lo.x = v[0] | (v[1] << 16);  lo.y = v[2] | (v[3] << 16);
                lo.z = v[4] | (v[5] << 16);  lo.w = v[6] | (v[7] << 16);
                hi.x = v[8] | (v[9] << 16);  hi.y = v[10] | (v[11] << 16);
                hi.z = v[12] | (v[13] << 16); hi.w = v[14] | (v[15] << 16);
                *(uint4*)(xsc + p * 16)             = lo;
                *(uint4*)(xsc + HALFBYTES + p * 16) = hi;
            }
            __syncthreads();

            // ---- GEMM over this slice: 13 K-steps x 16 pixel groups ----
            const unsigned short* kcs = kc + (size_t)(g * 4 + rbase) * 13 * 512;
            const char* wb = xsc + wave * 8 * ROWB;
            #pragma unroll
            for (int pp = 0; pp < 13; ++pp) {
                bf16x8 af = *(const bf16x8*)(kcs + pp * 512 + aoff);
                const char* wp = wb + boff[pp];
                #pragma unroll
                for (int pg = 0; pg < 16; ++pg) {
                    bf16x8 bf = *(const bf16x8*)(wp + (pg >> 1) * ROWB + (pg & 1) * 256);
                    acc[pg] = __builtin_amdgcn_mfma_f32_16x16x32_bf16(af, bf, acc[pg], 0, 0, 0);
                }
            }
        }
    }

    // ---- epilogue: D row = o = q*4+reg, col = pixel = n ----
    const size_t obase = ((size_t)b * COUT * NRS + g) * IMG;
    #pragma unroll
    for (int pg = 0; pg < 16; ++pg) {
        int row = th0 + wave * 8 + (pg >> 1);
        int col = tw0 + (pg & 1) * 16 + n;
        size_t pix = (size_t)row * HW + col;
        #pragma unroll
        for (int r = 0; r < 4; ++r) {
            int o = q * 4 + r;
            out[obase + (size_t)o * NRS * IMG + pix] = acc[pg][r];
        }
    }
}

extern "C" void kernel_launch(void* const* d_in, const int* in_sizes, int n_in,
                              void* d_out, int out_size, void* d_ws, size_t ws_size,
                              hipStream_t stream) {
    const float* x      = (const float*)d_in[0];
    const float* weight = (const float*)d_in[1];
    const float* basis  = (const float*)d_in[2];
    float* out = (float*)d_out;
    unsigned short* kc = (unsigned short*)d_ws;    // 639 KB

    build_kc<<<dim3((12 * 4 * 13 * 16 * 32 + 255) / 256), dim3(256), 0, stream>>>(weight, basis, kc);
    conv_mfma<<<dim3(16, NRS, 8), dim3(256), 0, stream>>>(x, kc, out);
}